// Round 1
// 1360.556 us; speedup vs baseline: 1.0623x; 1.0623x over previous
//
#include <hip/hip_runtime.h>
#include <hip/hip_fp16.h>
#include <math.h>

// Problem constants: H=4 heads, C=32, HID=128, 3 layers, B=2048, D=480
#define NHEAD   4
#define CDIM    32
#define HIDDIM  128
#define NLAYERS 3
#define DIN     480
#define LN_EPS  1e-5f
#define NSPLIT  4    // dst-range owners for locality-split CSR fill

typedef _Float16 f16x8 __attribute__((ext_vector_type(8)));
typedef float    f32x4 __attribute__((ext_vector_type(4)));

// ---------------------------------------------------------------------------
// Combined-graph CSR build. Node ids: tcr [0,Nt), pep [Nt,Nt+Np).
// ---------------------------------------------------------------------------
__global__ void hist_kernel(const int* __restrict__ tei, const int* __restrict__ pei,
                            int* __restrict__ deg, int Et, int Ep, int Nt, int N) {
    int i = blockIdx.x * 256 + threadIdx.x;
    int tot = Et + Ep + N;
    if (i >= tot) return;
    int d;
    if (i < Et)            d = tei[Et + i];
    else if (i < Et + Ep)  d = pei[Ep + (i - Et)] + Nt;
    else                   d = i - Et - Ep;
    atomicAdd(&deg[d], 1);
}

// Owner-split fill: blocks with blockIdx%NSPLIT==o only write edges whose dst
// falls in owner-range o (dst*NSPLIT/N). Under round-robin block->XCD dispatch
// this confines each 2.4MB col region to 2 XCDs' L2s over a short window, so
// scattered 4B writes combine into full lines before writeback (was 150MB
// WRITE_SIZE for 9.8MB payload). Edge-list dst reads replicate x4 but are
// L3-served.
__global__ __launch_bounds__(256) void fill_kernel(const int* __restrict__ tei,
                                                   const int* __restrict__ pei,
                                                   int* __restrict__ cursor,
                                                   int* __restrict__ col,
                                                   int Et, int Ep, int Nt, int N,
                                                   float oscale) {
    int oid    = blockIdx.x & (NSPLIT - 1);
    int chunk  = blockIdx.x / NSPLIT;
    int nchunk = gridDim.x / NSPLIT;
    int tot = Et + Ep + N;
    int per = (tot + nchunk - 1) / nchunk;
    int e0 = chunk * per;
    int e1 = min(e0 + per, tot);
    for (int i = e0 + (int)threadIdx.x; i < e1; i += 256) {
        int d;
        bool self = false;
        if (i < Et)           d = tei[Et + i];
        else if (i < Et + Ep) d = pei[Ep + (i - Et)] + Nt;
        else                { d = i - Et - Ep; self = true; }
        int owner = (int)((float)d * oscale);
        owner = owner > NSPLIT - 1 ? NSPLIT - 1 : owner;
        if (owner != oid) continue;
        int s;
        if (self)        s = d;
        else if (i < Et) s = tei[i];
        else             s = pei[i - Et] + Nt;
        int pos = atomicAdd(&cursor[d], 1);
        col[pos] = s;
    }
}

// ---------------------------------------------------------------------------
// Hierarchical exclusive scan: 1024 elems/block, int4 coalesced.
// ---------------------------------------------------------------------------
__global__ __launch_bounds__(256) void scan_reduce(const int* __restrict__ deg,
                                                   int* __restrict__ part, int N) {
    __shared__ int sm[256];
    int t = threadIdx.x;
    int base = blockIdx.x * 1024 + t * 4;
    int4 v = make_int4(0, 0, 0, 0);
    if (base + 3 < N) v = *(const int4*)(deg + base);
    else if (base < N) {
        v.x = deg[base];
        if (base + 1 < N) v.y = deg[base + 1];
        if (base + 2 < N) v.z = deg[base + 2];
    }
    sm[t] = v.x + v.y + v.z + v.w;
    __syncthreads();
    for (int off = 128; off >= 1; off >>= 1) {
        if (t < off) sm[t] += sm[t + off];
        __syncthreads();
    }
    if (t == 0) part[blockIdx.x] = sm[0];
}

__global__ __launch_bounds__(256) void scan_partials(int* __restrict__ part,
                                                     int* __restrict__ rowptr,
                                                     int npart, int N) {
    __shared__ int sm[256];
    int t = threadIdx.x;
    sm[t] = (t < npart) ? part[t] : 0;
    __syncthreads();
    for (int off = 1; off < 256; off <<= 1) {
        int u = (t >= off) ? sm[t - off] : 0;
        __syncthreads();
        sm[t] += u;
        __syncthreads();
    }
    if (t < npart) part[t] = (t == 0) ? 0 : sm[t - 1];
    if (t == 0) rowptr[N] = sm[255];
}

__global__ __launch_bounds__(256) void scan_final(const int* __restrict__ deg,
                                                  const int* __restrict__ part,
                                                  int* __restrict__ rowptr,
                                                  int* __restrict__ cursor, int N) {
    __shared__ int sm[256];
    int t = threadIdx.x;
    int base = blockIdx.x * 1024 + t * 4;
    int4 v = make_int4(0, 0, 0, 0);
    if (base + 3 < N) v = *(const int4*)(deg + base);
    else if (base < N) {
        v.x = deg[base];
        if (base + 1 < N) v.y = deg[base + 1];
        if (base + 2 < N) v.z = deg[base + 2];
    }
    sm[t] = v.x + v.y + v.z + v.w;
    __syncthreads();
    for (int off = 1; off < 256; off <<= 1) {
        int u = (t >= off) ? sm[t - off] : 0;
        __syncthreads();
        sm[t] += u;
        __syncthreads();
    }
    int run = ((t == 0) ? 0 : sm[t - 1]) + part[blockIdx.x];
    if (base < N)     { rowptr[base]     = run; cursor[base]     = run; run += v.x; }
    if (base + 1 < N) { rowptr[base + 1] = run; cursor[base + 1] = run; run += v.y; }
    if (base + 2 < N) { rowptr[base + 2] = run; cursor[base + 2] = run; run += v.z; }
    if (base + 3 < N) { rowptr[base + 3] = run; cursor[base + 3] = run; }
}

// ---------------------------------------------------------------------------
// Weight prep: W [K][128] f32 -> Wt [128][K] f16 (transposed, cast).
// ---------------------------------------------------------------------------
__global__ void transpose_w(const float* __restrict__ W, _Float16* __restrict__ Wt,
                            int K) {
    int idx = blockIdx.x * 256 + threadIdx.x;
    if (idx >= K * 128) return;
    int n = idx / K, k = idx - n * K;
    Wt[idx] = (_Float16)W[(size_t)k * 128 + n];
}

// ---------------------------------------------------------------------------
// MFMA fp16 GEMM: C[n,j] = act(A[n,:] @ W[:,j] (+bias)), 128 output cols.
// Block 256 (4 waves); tile 64 rows x 128 cols; K-step 32.
// Wt is pre-transposed [128][K] f16. A is f32, cast to f16 during staging.
// Fragment layouts (gfx950 16x16x32): A/B lane: [m|n=lane&15][k=quad*8+j];
// C/D lane: col=lane&15, row=quad*4+reg.   OUT_F16: f16 out, no bias/act.
// ---------------------------------------------------------------------------
#define ASTRIDE 40   // halves; 80 B row stride: 16B-aligned, 2-way banks (free)

template<int OUT_F16>
__global__ __launch_bounds__(256) void mfma_gemm(const float* __restrict__ A,
                                                 const _Float16* __restrict__ Wt,
                                                 const float* __restrict__ bias,
                                                 void* __restrict__ Cout,
                                                 int K) {
    __shared__ _Float16 As[64 * ASTRIDE];
    __shared__ _Float16 Ws[128 * ASTRIDE];
    const int tid  = threadIdx.x;
    const int bn   = blockIdx.x * 64;
    const int wave = tid >> 6, lane = tid & 63;
    const int lm   = lane & 15, q = lane >> 4;

    f32x4 acc[8];
#pragma unroll
    for (int i = 0; i < 8; ++i) acc[i] = (f32x4){0.f, 0.f, 0.f, 0.f};

    for (int kt = 0; kt < K; kt += 32) {
        // Stage A tile: 64 rows x 32 cols, f32 -> f16 (coalesced float4 loads)
#pragma unroll
        for (int p = 0; p < 2; ++p) {
            int f  = p * 256 + tid;          // float4 index in [0,512)
            int r  = f >> 3;
            int c4 = (f & 7) * 4;
            float4 v = *(const float4*)(A + (size_t)(bn + r) * K + kt + c4);
            _Float16* d = &As[r * ASTRIDE + c4];
            d[0] = (_Float16)v.x; d[1] = (_Float16)v.y;
            d[2] = (_Float16)v.z; d[3] = (_Float16)v.w;
        }
        // Stage Wt tile: 128 rows(n) x 32 k halves (straight copy, coalesced)
#pragma unroll
        for (int p = 0; p < 2; ++p) {
            int f   = p * 256 + tid;         // 8-half segment index in [0,512)
            int n   = f >> 2;
            int seg = (f & 3) * 8;
            *(float4*)(&Ws[n * ASTRIDE + seg]) =
                *(const float4*)(Wt + (size_t)n * K + kt + seg);
        }
        __syncthreads();
        f16x8 af = *(const f16x8*)(&As[(wave * 16 + lm) * ASTRIDE + q * 8]);
#pragma unroll
        for (int nt = 0; nt < 8; ++nt) {
            f16x8 bf = *(const f16x8*)(&Ws[(nt * 16 + lm) * ASTRIDE + q * 8]);
            acc[nt] = __builtin_amdgcn_mfma_f32_16x16x32_f16(af, bf, acc[nt], 0, 0, 0);
        }
        __syncthreads();
    }

    const int row0 = bn + wave * 16 + q * 4;
    if (OUT_F16) {
        _Float16* C = (_Float16*)Cout;
#pragma unroll
        for (int nt = 0; nt < 8; ++nt) {
            int c = nt * 16 + lm;
#pragma unroll
            for (int i = 0; i < 4; ++i)
                C[(size_t)(row0 + i) * 128 + c] = (_Float16)acc[nt][i];
        }
    } else {
        float* C = (float*)Cout;
#pragma unroll
        for (int nt = 0; nt < 8; ++nt) {
            int c = nt * 16 + lm;
            float bv = bias[c];
#pragma unroll
            for (int i = 0; i < 4; ++i)
                C[(size_t)(row0 + i) * 128 + c] = fmaxf(acc[nt][i] + bv, 0.f);
        }
    }
}

// ---------------------------------------------------------------------------
// Attention scores from fp16 h2. One wave per node; lane l -> ch 2l,2l+1,
// head = l>>4. 16-lane group reduction -> ssrc[n*4+h], sdst[n*4+h].
// ---------------------------------------------------------------------------
__global__ __launch_bounds__(256) void scores_kernel(const __half2* __restrict__ h2v,
                                                     const float* __restrict__ a_src,
                                                     const float* __restrict__ a_dst,
                                                     float* __restrict__ ssrc,
                                                     float* __restrict__ sdst, int N) {
    int wave = threadIdx.x >> 6, lane = threadIdx.x & 63;
    int n = blockIdx.x * 4 + wave;
    if (n >= N) return;
    int c = lane * 2, h = lane >> 4, t = lane & 15;
    float2 v = __half22float2(h2v[(size_t)n * 64 + lane]);
    float2 as = *(const float2*)(a_src + c);
    float2 ad = *(const float2*)(a_dst + c);
    float ps = v.x * as.x + v.y * as.y;
    float pd = v.x * ad.x + v.y * ad.y;
#pragma unroll
    for (int k = 1; k < 16; k <<= 1) {
        ps += __shfl_xor(ps, k, 16);
        pd += __shfl_xor(pd, k, 16);
    }
    if (t == 0) {
        ssrc[n * 4 + h] = ps;
        sdst[n * 4 + h] = pd;
    }
}

// ---------------------------------------------------------------------------
// Fused gather with ONLINE softmax: per node, single pass over in-edges
// computing e = leakyrelu(ssrc[s]+sdst[n]) in-register (ssrc is L2-resident,
// 2.5MB), running-max rescale (r=exp(m-nm), always-multiply: branch-free),
// a += p*v, z += p. Replaces the 2-pass alpha_kernel + 39MB alpha buffer
// per layer. Then /z + bias + LayerNorm + ReLU + residual. One wave per node.
// a/z is invariant to the staged rescaling (~1e-7 rel vs fp16's 2^-8 floor).
// ---------------------------------------------------------------------------
__global__ __launch_bounds__(256) void gather_kernel(const __half2* __restrict__ h2v,
                                                     const float* __restrict__ ssrc,
                                                     const float* __restrict__ sdst,
                                                     const int* __restrict__ rowptr,
                                                     const int* __restrict__ col,
                                                     const float* __restrict__ bg,
                                                     const float* __restrict__ gamma,
                                                     const float* __restrict__ beta,
                                                     float* __restrict__ hio, int N) {
    int wave = threadIdx.x >> 6, lane = threadIdx.x & 63;
    int n = blockIdx.x * 4 + wave;
    if (n >= N) return;
    int c = lane * 2, h = lane >> 4;
    int beg = rowptr[n], end = rowptr[n + 1];
    float sd = sdst[n * 4 + h];
    float m = -1e30f, z = 0.f, a0 = 0.f, a1 = 0.f;
    int j = beg;
    for (; j + 3 < end; j += 4) {
        int s0 = col[j], s1 = col[j + 1], s2 = col[j + 2], s3 = col[j + 3];
        float e0 = ssrc[s0 * 4 + h] + sd;
        float e1 = ssrc[s1 * 4 + h] + sd;
        float e2 = ssrc[s2 * 4 + h] + sd;
        float e3 = ssrc[s3 * 4 + h] + sd;
        float2 v0 = __half22float2(h2v[(size_t)s0 * 64 + lane]);
        float2 v1 = __half22float2(h2v[(size_t)s1 * 64 + lane]);
        float2 v2 = __half22float2(h2v[(size_t)s2 * 64 + lane]);
        float2 v3 = __half22float2(h2v[(size_t)s3 * 64 + lane]);
        e0 = e0 > 0.f ? e0 : 0.2f * e0;
        e1 = e1 > 0.f ? e1 : 0.2f * e1;
        e2 = e2 > 0.f ? e2 : 0.2f * e2;
        e3 = e3 > 0.f ? e3 : 0.2f * e3;
        float nm = fmaxf(fmaxf(fmaxf(e0, e1), fmaxf(e2, e3)), m);
        float r  = __expf(m - nm);      // ==0 on first iter (m=-1e30), ==1 if no new max
        m = nm;
        float p0 = __expf(e0 - nm);
        float p1 = __expf(e1 - nm);
        float p2 = __expf(e2 - nm);
        float p3 = __expf(e3 - nm);
        a0 *= r; a1 *= r; z *= r;
        a0 = fmaf(p0, v0.x, a0); a1 = fmaf(p0, v0.y, a1);
        a0 = fmaf(p1, v1.x, a0); a1 = fmaf(p1, v1.y, a1);
        a0 = fmaf(p2, v2.x, a0); a1 = fmaf(p2, v2.y, a1);
        a0 = fmaf(p3, v3.x, a0); a1 = fmaf(p3, v3.y, a1);
        z += p0 + p1 + p2 + p3;
    }
    for (; j < end; ++j) {
        int s = col[j];
        float e = ssrc[s * 4 + h] + sd;
        e = e > 0.f ? e : 0.2f * e;
        float2 v = __half22float2(h2v[(size_t)s * 64 + lane]);
        float nm = fmaxf(m, e);
        float r  = __expf(m - nm);
        float p  = __expf(e - nm);
        m = nm;
        a0 = fmaf(p, v.x, a0 * r);
        a1 = fmaf(p, v.y, a1 * r);
        z  = z * r + p;
    }
    float inv = 1.f / z;
    float2 bgv = *(const float2*)(bg + c);
    float o0 = a0 * inv + bgv.x;
    float o1 = a1 * inv + bgv.y;
    float s = o0 + o1;
#pragma unroll
    for (int k = 1; k < 64; k <<= 1) s += __shfl_xor(s, k);
    float mu = s * (1.f / 128.f);
    float q = (o0 - mu) * (o0 - mu) + (o1 - mu) * (o1 - mu);
#pragma unroll
    for (int k = 1; k < 64; k <<= 1) q += __shfl_xor(q, k);
    float rs = rsqrtf(q * (1.f / 128.f) + LN_EPS);
    float2 gm = *(const float2*)(gamma + c);
    float2 bt = *(const float2*)(beta + c);
    float y0 = (o0 - mu) * rs * gm.x + bt.x;
    float y1 = (o1 - mu) * rs * gm.y + bt.y;
    float2 r = *(const float2*)(hio + (size_t)n * 128 + c);
    y0 = fmaxf(y0, 0.f) + r.x;
    y1 = fmaxf(y1, 0.f) + r.y;
    *(float2*)(hio + (size_t)n * 128 + c) = make_float2(y0, y1);
}

// ---------------------------------------------------------------------------
// Global mean pool. tcr -> pooled[b][0:128], cnt[b]; pep -> [128:256], cnt[B+b].
// ---------------------------------------------------------------------------
__global__ __launch_bounds__(256) void pool_kernel(const float* __restrict__ h,
                                                   const int* __restrict__ tb,
                                                   const int* __restrict__ pb,
                                                   float* __restrict__ pooled,
                                                   int* __restrict__ cnt,
                                                   int Nt, int N, int B) {
    int wave = threadIdx.x >> 6, lane = threadIdx.x & 63;
    int n = blockIdx.x * 4 + wave;
    if (n >= N) return;
    int b, off, ci;
    if (n < Nt) { b = tb[n];      off = 0;   ci = b; }
    else        { b = pb[n - Nt]; off = 128; ci = B + b; }
    float v0 = h[(size_t)n * 128 + lane];
    float v1 = h[(size_t)n * 128 + 64 + lane];
    atomicAdd(&pooled[(size_t)b * 256 + off + lane], v0);
    atomicAdd(&pooled[(size_t)b * 256 + off + 64 + lane], v1);
    if (lane == 0) atomicAdd(&cnt[ci], 1);
}

// ---------------------------------------------------------------------------
// Classifier MLP: [B,256] -> relu 128 -> relu 64 -> sigmoid 1. Block per row.
// ---------------------------------------------------------------------------
__global__ __launch_bounds__(128) void classifier_kernel(const float* __restrict__ pooled,
                                                         const int* __restrict__ cnt,
                                                         const float* __restrict__ Wc1,
                                                         const float* __restrict__ bc1,
                                                         const float* __restrict__ Wc2,
                                                         const float* __restrict__ bc2,
                                                         const float* __restrict__ Wc3,
                                                         const float* __restrict__ bc3,
                                                         float* __restrict__ outp, int B) {
    __shared__ float z[256];
    __shared__ float a1[128];
    __shared__ float a2[64];
    int r = blockIdx.x, t = threadIdx.x;
    float ct = (float)max(cnt[r], 1);
    float cp = (float)max(cnt[B + r], 1);
    z[t]       = pooled[(size_t)r * 256 + t] / ct;
    z[128 + t] = pooled[(size_t)r * 256 + 128 + t] / cp;
    __syncthreads();
    float acc = bc1[t];
    for (int k = 0; k < 256; ++k) acc = fmaf(z[k], Wc1[k * 128 + t], acc);
    a1[t] = fmaxf(acc, 0.f);
    __syncthreads();
    if (t < 64) {
        float a = bc2[t];
        for (int k = 0; k < 128; ++k) a = fmaf(a1[k], Wc2[k * 64 + t], a);
        a2[t] = fmaxf(a, 0.f);
    }
    __syncthreads();
    if (t < 64) {
        float p = a2[t] * Wc3[t];
#pragma unroll
        for (int k = 1; k < 64; k <<= 1) p += __shfl_xor(p, k);
        if (t == 0) outp[r] = 1.f / (1.f + __expf(-(p + bc3[0])));
    }
}

// ---------------------------------------------------------------------------
// Host orchestration — combined graph, fp16 MFMA GEMMs, fused softmax/gather.
// ---------------------------------------------------------------------------
extern "C" void kernel_launch(void* const* d_in, const int* in_sizes, int n_in,
                              void* d_out, int out_size, void* d_ws, size_t ws_size,
                              hipStream_t stream) {
    const float* tcr_x     = (const float*)d_in[0];
    const int*   tcr_ei    = (const int*)d_in[1];
    const int*   tcr_batch = (const int*)d_in[2];
    const float* pep_x     = (const float*)d_in[3];
    const int*   pep_ei    = (const int*)d_in[4];
    const int*   pep_batch = (const int*)d_in[5];
    const float* W_in      = (const float*)d_in[6];
    const float* b_in      = (const float*)d_in[7];
    const float* Wg        = (const float*)d_in[8];
    const float* bg        = (const float*)d_in[9];
    const float* att_src   = (const float*)d_in[10];
    const float* att_dst   = (const float*)d_in[11];
    const float* ln_gamma  = (const float*)d_in[12];
    const float* ln_beta   = (const float*)d_in[13];
    const float* Wc1       = (const float*)d_in[14];
    const float* bc1       = (const float*)d_in[15];
    const float* Wc2       = (const float*)d_in[16];
    const float* bc2       = (const float*)d_in[17];
    const float* Wc3       = (const float*)d_in[18];
    const float* bc3       = (const float*)d_in[19];

    const int Nt = in_sizes[0] / DIN;
    const int Et = in_sizes[1] / 2;
    const int Np = in_sizes[3] / DIN;
    const int Ep = in_sizes[4] / 2;
    const int B  = out_size;
    const int N  = Nt + Np;
    const int Etot = Et + Ep + N;

    char* w = (char*)d_ws;
    size_t o = 0;
    auto alloc = [&](size_t bytes) -> char* {
        size_t r = (o + 255) & ~(size_t)255;
        o = r + bytes;
        return w + r;
    };
    float*    pooled = (float*)alloc((size_t)B * 256 * 4);
    int*      cnt    = (int*)alloc((size_t)B * 2 * 4);
    float*    h_a    = (float*)alloc((size_t)N * 128 * 4);   // residual stream (f32)
    _Float16* h2h    = (_Float16*)alloc((size_t)N * 128 * 2); // projected feats (f16)
    _Float16* WtIn   = (_Float16*)alloc((size_t)128 * DIN * 2);
    _Float16* WtG    = (_Float16*)alloc((size_t)NLAYERS * 128 * 128 * 2);
    float*    ssrc   = (float*)alloc((size_t)N * 4 * 4);
    float*    sdst   = (float*)alloc((size_t)N * 4 * 4);
    int* rowptr      = (int*)alloc((size_t)(N + 1) * 4);
    int* cursor      = (int*)alloc((size_t)N * 4);
    int* deg         = (int*)alloc((size_t)N * 4);
    int* part        = (int*)alloc(256 * 4);
    int* col         = (int*)alloc((size_t)Etot * 4);
    (void)ws_size; (void)n_in;

    hipMemsetAsync(pooled, 0, (size_t)B * 256 * 4, stream);
    hipMemsetAsync(cnt, 0, (size_t)B * 2 * 4, stream);
    hipMemsetAsync(deg, 0, (size_t)N * 4, stream);

    // Weight prep (transpose + f16 cast)
    transpose_w<<<(128 * DIN + 255) / 256, 256, 0, stream>>>(W_in, WtIn, DIN);
    for (int i = 0; i < NLAYERS; ++i)
        transpose_w<<<(128 * 128 + 255) / 256, 256, 0, stream>>>(
            Wg + (size_t)i * HIDDIM * HIDDIM, WtG + (size_t)i * 128 * 128, 128);

    // CSR build (combined, built once, reused by all 3 layers)
    hist_kernel<<<(Etot + 255) / 256, 256, 0, stream>>>(tcr_ei, pep_ei, deg, Et, Ep, Nt, N);
    int nblk = (N + 1023) / 1024;
    scan_reduce<<<nblk, 256, 0, stream>>>(deg, part, N);
    scan_partials<<<1, 256, 0, stream>>>(part, rowptr, nblk, N);
    scan_final<<<nblk, 256, 0, stream>>>(deg, part, rowptr, cursor, N);
    // Owner-split fill: 4 owners x 512 chunks = 2048 blocks
    fill_kernel<<<NSPLIT * 512, 256, 0, stream>>>(tcr_ei, pep_ei, cursor, col,
                                                  Et, Ep, Nt, N, (float)NSPLIT / (float)N);

    // Input projection + relu -> combined residual stream (MFMA f16)
    mfma_gemm<0><<<Nt / 64, 256, 0, stream>>>(tcr_x, WtIn, b_in, h_a, DIN);
    mfma_gemm<0><<<Np / 64, 256, 0, stream>>>(pep_x, WtIn, b_in, h_a + (size_t)Nt * 128, DIN);

    for (int i = 0; i < NLAYERS; ++i) {
        mfma_gemm<1><<<N / 64, 256, 0, stream>>>(h_a, WtG + (size_t)i * 128 * 128,
                                                 nullptr, h2h, 128);
        scores_kernel<<<(N + 3) / 4, 256, 0, stream>>>((const __half2*)h2h,
                                                       att_src + i * NHEAD * CDIM,
                                                       att_dst + i * NHEAD * CDIM,
                                                       ssrc, sdst, N);
        gather_kernel<<<(N + 3) / 4, 256, 0, stream>>>((const __half2*)h2h, ssrc, sdst,
                                                       rowptr, col, bg + i * HIDDIM,
                                                       ln_gamma + i * HIDDIM,
                                                       ln_beta + i * HIDDIM, h_a, N);
    }
    pool_kernel<<<(N + 3) / 4, 256, 0, stream>>>(h_a, tcr_batch, pep_batch, pooled, cnt, Nt, N, B);

    classifier_kernel<<<B, 128, 0, stream>>>(pooled, cnt, Wc1, bc1, Wc2, bc2,
                                             Wc3, bc3, (float*)d_out, B);
}

// Round 2
// 1292.668 us; speedup vs baseline: 1.1181x; 1.0525x over previous
//
#include <hip/hip_runtime.h>
#include <hip/hip_fp16.h>
#include <math.h>

// Problem constants: H=4 heads, C=32, HID=128, 3 layers, B=2048, D=480
#define NHEAD   4
#define CDIM    32
#define HIDDIM  128
#define NLAYERS 3
#define DIN     480
#define LN_EPS  1e-5f
#define NSPLIT  4    // dst-range owners for locality-split CSR fill

typedef _Float16 f16x8 __attribute__((ext_vector_type(8)));
typedef float    f32x4 __attribute__((ext_vector_type(4)));
typedef int      int4u __attribute__((ext_vector_type(4), aligned(4)));  // 4B-aligned int4 load

// ---------------------------------------------------------------------------
// Combined-graph CSR build. Node ids: tcr [0,Nt), pep [Nt,Nt+Np).
// ---------------------------------------------------------------------------
__global__ void hist_kernel(const int* __restrict__ tei, const int* __restrict__ pei,
                            int* __restrict__ deg, int Et, int Ep, int Nt, int N) {
    int i = blockIdx.x * 256 + threadIdx.x;
    int tot = Et + Ep + N;
    if (i >= tot) return;
    int d;
    if (i < Et)            d = tei[Et + i];
    else if (i < Et + Ep)  d = pei[Ep + (i - Et)] + Nt;
    else                   d = i - Et - Ep;
    atomicAdd(&deg[d], 1);
}

// Owner-split fill: blocks with blockIdx%NSPLIT==o only write edges whose dst
// falls in owner-range o (dst*NSPLIT/N). Confines each col region to ~2 XCDs'
// L2s over a short window so scattered 4B writes combine into full lines
// (WRITE_SIZE was 150MB for a 9.8MB payload before; ~6x less after).
__global__ __launch_bounds__(256) void fill_kernel(const int* __restrict__ tei,
                                                   const int* __restrict__ pei,
                                                   int* __restrict__ cursor,
                                                   int* __restrict__ col,
                                                   int Et, int Ep, int Nt, int N,
                                                   float oscale) {
    int oid    = blockIdx.x & (NSPLIT - 1);
    int chunk  = blockIdx.x / NSPLIT;
    int nchunk = gridDim.x / NSPLIT;
    int tot = Et + Ep + N;
    int per = (tot + nchunk - 1) / nchunk;
    int e0 = chunk * per;
    int e1 = min(e0 + per, tot);
    for (int i = e0 + (int)threadIdx.x; i < e1; i += 256) {
        int d;
        bool self = false;
        if (i < Et)           d = tei[Et + i];
        else if (i < Et + Ep) d = pei[Ep + (i - Et)] + Nt;
        else                { d = i - Et - Ep; self = true; }
        int owner = (int)((float)d * oscale);
        owner = owner > NSPLIT - 1 ? NSPLIT - 1 : owner;
        if (owner != oid) continue;
        int s;
        if (self)        s = d;
        else if (i < Et) s = tei[i];
        else             s = pei[i - Et] + Nt;
        int pos = atomicAdd(&cursor[d], 1);
        col[pos] = s;
    }
}

// ---------------------------------------------------------------------------
// Hierarchical exclusive scan: 1024 elems/block, int4 coalesced.
// ---------------------------------------------------------------------------
__global__ __launch_bounds__(256) void scan_reduce(const int* __restrict__ deg,
                                                   int* __restrict__ part, int N) {
    __shared__ int sm[256];
    int t = threadIdx.x;
    int base = blockIdx.x * 1024 + t * 4;
    int4 v = make_int4(0, 0, 0, 0);
    if (base + 3 < N) v = *(const int4*)(deg + base);
    else if (base < N) {
        v.x = deg[base];
        if (base + 1 < N) v.y = deg[base + 1];
        if (base + 2 < N) v.z = deg[base + 2];
    }
    sm[t] = v.x + v.y + v.z + v.w;
    __syncthreads();
    for (int off = 128; off >= 1; off >>= 1) {
        if (t < off) sm[t] += sm[t + off];
        __syncthreads();
    }
    if (t == 0) part[blockIdx.x] = sm[0];
}

__global__ __launch_bounds__(256) void scan_partials(int* __restrict__ part,
                                                     int* __restrict__ rowptr,
                                                     int npart, int N) {
    __shared__ int sm[256];
    int t = threadIdx.x;
    sm[t] = (t < npart) ? part[t] : 0;
    __syncthreads();
    for (int off = 1; off < 256; off <<= 1) {
        int u = (t >= off) ? sm[t - off] : 0;
        __syncthreads();
        sm[t] += u;
        __syncthreads();
    }
    if (t < npart) part[t] = (t == 0) ? 0 : sm[t - 1];
    if (t == 0) rowptr[N] = sm[255];
}

__global__ __launch_bounds__(256) void scan_final(const int* __restrict__ deg,
                                                  const int* __restrict__ part,
                                                  int* __restrict__ rowptr,
                                                  int* __restrict__ cursor, int N) {
    __shared__ int sm[256];
    int t = threadIdx.x;
    int base = blockIdx.x * 1024 + t * 4;
    int4 v = make_int4(0, 0, 0, 0);
    if (base + 3 < N) v = *(const int4*)(deg + base);
    else if (base < N) {
        v.x = deg[base];
        if (base + 1 < N) v.y = deg[base + 1];
        if (base + 2 < N) v.z = deg[base + 2];
    }
    sm[t] = v.x + v.y + v.z + v.w;
    __syncthreads();
    for (int off = 1; off < 256; off <<= 1) {
        int u = (t >= off) ? sm[t - off] : 0;
        __syncthreads();
        sm[t] += u;
        __syncthreads();
    }
    int run = ((t == 0) ? 0 : sm[t - 1]) + part[blockIdx.x];
    if (base < N)     { rowptr[base]     = run; cursor[base]     = run; run += v.x; }
    if (base + 1 < N) { rowptr[base + 1] = run; cursor[base + 1] = run; run += v.y; }
    if (base + 2 < N) { rowptr[base + 2] = run; cursor[base + 2] = run; run += v.z; }
    if (base + 3 < N) { rowptr[base + 3] = run; cursor[base + 3] = run; }
}

// ---------------------------------------------------------------------------
// Weight prep: W [K][128] f32 -> Wt [128][K] f16 (transposed, cast).
// ---------------------------------------------------------------------------
__global__ void transpose_w(const float* __restrict__ W, _Float16* __restrict__ Wt,
                            int K) {
    int idx = blockIdx.x * 256 + threadIdx.x;
    if (idx >= K * 128) return;
    int n = idx / K, k = idx - n * K;
    Wt[idx] = (_Float16)W[(size_t)k * 128 + n];
}

// ---------------------------------------------------------------------------
// MFMA fp16 GEMM: C[n,j] = act(A[n,:] @ W[:,j] (+bias)), 128 output cols.
// Block 256 (4 waves); tile 64 rows x 128 cols; K-step 32.
// Wt is pre-transposed [128][K] f16. A is f32, cast to f16 during staging.
// Fragment layouts (gfx950 16x16x32): A/B lane: [m|n=lane&15][k=quad*8+j];
// C/D lane: col=lane&15, row=quad*4+reg.   OUT_F16: f16 out, no bias/act.
// ---------------------------------------------------------------------------
#define ASTRIDE 40   // halves; 80 B row stride: 16B-aligned, 2-way banks (free)

template<int OUT_F16>
__global__ __launch_bounds__(256) void mfma_gemm(const float* __restrict__ A,
                                                 const _Float16* __restrict__ Wt,
                                                 const float* __restrict__ bias,
                                                 void* __restrict__ Cout,
                                                 int K) {
    __shared__ _Float16 As[64 * ASTRIDE];
    __shared__ _Float16 Ws[128 * ASTRIDE];
    const int tid  = threadIdx.x;
    const int bn   = blockIdx.x * 64;
    const int wave = tid >> 6, lane = tid & 63;
    const int lm   = lane & 15, q = lane >> 4;

    f32x4 acc[8];
#pragma unroll
    for (int i = 0; i < 8; ++i) acc[i] = (f32x4){0.f, 0.f, 0.f, 0.f};

    for (int kt = 0; kt < K; kt += 32) {
        // Stage A tile: 64 rows x 32 cols, f32 -> f16 (coalesced float4 loads)
#pragma unroll
        for (int p = 0; p < 2; ++p) {
            int f  = p * 256 + tid;          // float4 index in [0,512)
            int r  = f >> 3;
            int c4 = (f & 7) * 4;
            float4 v = *(const float4*)(A + (size_t)(bn + r) * K + kt + c4);
            _Float16* d = &As[r * ASTRIDE + c4];
            d[0] = (_Float16)v.x; d[1] = (_Float16)v.y;
            d[2] = (_Float16)v.z; d[3] = (_Float16)v.w;
        }
        // Stage Wt tile: 128 rows(n) x 32 k halves (straight copy, coalesced)
#pragma unroll
        for (int p = 0; p < 2; ++p) {
            int f   = p * 256 + tid;         // 8-half segment index in [0,512)
            int n   = f >> 2;
            int seg = (f & 3) * 8;
            *(float4*)(&Ws[n * ASTRIDE + seg]) =
                *(const float4*)(Wt + (size_t)n * K + kt + seg);
        }
        __syncthreads();
        f16x8 af = *(const f16x8*)(&As[(wave * 16 + lm) * ASTRIDE + q * 8]);
#pragma unroll
        for (int nt = 0; nt < 8; ++nt) {
            f16x8 bf = *(const f16x8*)(&Ws[(nt * 16 + lm) * ASTRIDE + q * 8]);
            acc[nt] = __builtin_amdgcn_mfma_f32_16x16x32_f16(af, bf, acc[nt], 0, 0, 0);
        }
        __syncthreads();
    }

    const int row0 = bn + wave * 16 + q * 4;
    if (OUT_F16) {
        _Float16* C = (_Float16*)Cout;
#pragma unroll
        for (int nt = 0; nt < 8; ++nt) {
            int c = nt * 16 + lm;
#pragma unroll
            for (int i = 0; i < 4; ++i)
                C[(size_t)(row0 + i) * 128 + c] = (_Float16)acc[nt][i];
        }
    } else {
        float* C = (float*)Cout;
#pragma unroll
        for (int nt = 0; nt < 8; ++nt) {
            int c = nt * 16 + lm;
            float bv = bias[c];
#pragma unroll
            for (int i = 0; i < 4; ++i)
                C[(size_t)(row0 + i) * 128 + c] = fmaxf(acc[nt][i] + bv, 0.f);
        }
    }
}

// ---------------------------------------------------------------------------
// Attention scores from fp16 h2. One wave per node; lane l -> ch 2l,2l+1,
// head = l>>4. 16-lane group reduction -> ssrc[n*4+h], sdst[n*4+h].
// ---------------------------------------------------------------------------
__global__ __launch_bounds__(256) void scores_kernel(const __half2* __restrict__ h2v,
                                                     const float* __restrict__ a_src,
                                                     const float* __restrict__ a_dst,
                                                     float* __restrict__ ssrc,
                                                     float* __restrict__ sdst, int N) {
    int wave = threadIdx.x >> 6, lane = threadIdx.x & 63;
    int n = blockIdx.x * 4 + wave;
    if (n >= N) return;
    int c = lane * 2, h = lane >> 4, t = lane & 15;
    float2 v = __half22float2(h2v[(size_t)n * 64 + lane]);
    float2 as = *(const float2*)(a_src + c);
    float2 ad = *(const float2*)(a_dst + c);
    float ps = v.x * as.x + v.y * as.y;
    float pd = v.x * ad.x + v.y * ad.y;
#pragma unroll
    for (int k = 1; k < 16; k <<= 1) {
        ps += __shfl_xor(ps, k, 16);
        pd += __shfl_xor(pd, k, 16);
    }
    if (t == 0) {
        ssrc[n * 4 + h] = ps;
        sdst[n * 4 + h] = pd;
    }
}

// ---------------------------------------------------------------------------
// Fused gather with ONLINE softmax — 4 nodes per wave, 16 lanes per node,
// 8 channels per lane (one f16x8/dwordx4 value load per lane per edge).
// All scalar-ish per-edge work (col int4 load, ssrc load, leaky-relu, exp,
// online-max rescale) amortizes over 4 edges per wave-instruction (was 1).
// FMAs use (float)half * float + float so clang emits v_fma_mix_f32.
// Then /z + bias + LayerNorm (16-lane reduce) + ReLU + residual.
// ---------------------------------------------------------------------------
__global__ __launch_bounds__(256) void gather_kernel(const f16x8* __restrict__ h2v,
                                                     const float* __restrict__ ssrc,
                                                     const float* __restrict__ sdst,
                                                     const int* __restrict__ rowptr,
                                                     const int* __restrict__ col,
                                                     const float* __restrict__ bg,
                                                     const float* __restrict__ gamma,
                                                     const float* __restrict__ beta,
                                                     float* __restrict__ hio, int N) {
    int wave = threadIdx.x >> 6, lane = threadIdx.x & 63;
    int g = lane >> 4, t = lane & 15;       // group g handles node n; lane t -> ch [8t,8t+8)
    int n = blockIdx.x * 16 + wave * 4 + g;
    bool valid = n < N;
    int nn = valid ? n : 0;
    int head = t >> 2;
    int beg = rowptr[nn];
    int end = valid ? rowptr[nn + 1] : beg;
    float sd = sdst[nn * 4 + head];

    float m = -1e30f, z = 0.f;
    float a[8];
#pragma unroll
    for (int k = 0; k < 8; ++k) a[k] = 0.f;

    int j = beg;
    for (; j + 3 < end; j += 4) {
        int4u cv = *(const int4u*)(col + j);
        int s0 = cv.x, s1 = cv.y, s2 = cv.z, s3 = cv.w;
        float e0 = ssrc[s0 * 4 + head] + sd;
        float e1 = ssrc[s1 * 4 + head] + sd;
        float e2 = ssrc[s2 * 4 + head] + sd;
        float e3 = ssrc[s3 * 4 + head] + sd;
        f16x8 v0 = h2v[(size_t)s0 * 16 + t];
        f16x8 v1 = h2v[(size_t)s1 * 16 + t];
        f16x8 v2 = h2v[(size_t)s2 * 16 + t];
        f16x8 v3 = h2v[(size_t)s3 * 16 + t];
        e0 = fmaxf(e0, 0.2f * e0);          // leaky_relu(x) = max(x, 0.2x)
        e1 = fmaxf(e1, 0.2f * e1);
        e2 = fmaxf(e2, 0.2f * e2);
        e3 = fmaxf(e3, 0.2f * e3);
        float nm = fmaxf(fmaxf(fmaxf(e0, e1), fmaxf(e2, e3)), m);
        float r  = __expf(m - nm);          // 0 on first chunk, 1 if no new max
        m = nm;
        float p0 = __expf(e0 - nm);
        float p1 = __expf(e1 - nm);
        float p2 = __expf(e2 - nm);
        float p3 = __expf(e3 - nm);
        z = z * r + (p0 + p1 + p2 + p3);
#pragma unroll
        for (int k = 0; k < 8; ++k) a[k] *= r;
#pragma unroll
        for (int k = 0; k < 8; ++k) a[k] = fmaf((float)v0[k], p0, a[k]);
#pragma unroll
        for (int k = 0; k < 8; ++k) a[k] = fmaf((float)v1[k], p1, a[k]);
#pragma unroll
        for (int k = 0; k < 8; ++k) a[k] = fmaf((float)v2[k], p2, a[k]);
#pragma unroll
        for (int k = 0; k < 8; ++k) a[k] = fmaf((float)v3[k], p3, a[k]);
    }
    for (; j < end; ++j) {
        int s = col[j];
        float e = ssrc[s * 4 + head] + sd;
        e = fmaxf(e, 0.2f * e);
        f16x8 v = h2v[(size_t)s * 16 + t];
        float nm = fmaxf(m, e);
        float r  = __expf(m - nm);
        float p  = __expf(e - nm);
        m = nm;
        z = z * r + p;
#pragma unroll
        for (int k = 0; k < 8; ++k) a[k] = fmaf((float)v[k], p, a[k] * r);
    }

    if (!valid) return;
    float inv = 1.f / z;
    int c0 = t * 8;
    float4 bgv0 = *(const float4*)(bg + c0);
    float4 bgv1 = *(const float4*)(bg + c0 + 4);
    float o[8];
    o[0] = a[0] * inv + bgv0.x; o[1] = a[1] * inv + bgv0.y;
    o[2] = a[2] * inv + bgv0.z; o[3] = a[3] * inv + bgv0.w;
    o[4] = a[4] * inv + bgv1.x; o[5] = a[5] * inv + bgv1.y;
    o[6] = a[6] * inv + bgv1.z; o[7] = a[7] * inv + bgv1.w;
    float s = 0.f;
#pragma unroll
    for (int k = 0; k < 8; ++k) s += o[k];
#pragma unroll
    for (int k = 1; k < 16; k <<= 1) s += __shfl_xor(s, k, 16);
    float mu = s * (1.f / 128.f);
    float q = 0.f;
#pragma unroll
    for (int k = 0; k < 8; ++k) q += (o[k] - mu) * (o[k] - mu);
#pragma unroll
    for (int k = 1; k < 16; k <<= 1) q += __shfl_xor(q, k, 16);
    float rs = rsqrtf(q * (1.f / 128.f) + LN_EPS);
    float4 gm0 = *(const float4*)(gamma + c0);
    float4 gm1 = *(const float4*)(gamma + c0 + 4);
    float4 bt0 = *(const float4*)(beta + c0);
    float4 bt1 = *(const float4*)(beta + c0 + 4);
    float* hrow = hio + (size_t)n * 128 + c0;
    float4 r0 = *(const float4*)(hrow);
    float4 r1 = *(const float4*)(hrow + 4);
    float4 y0, y1;
    y0.x = fmaxf((o[0] - mu) * rs * gm0.x + bt0.x, 0.f) + r0.x;
    y0.y = fmaxf((o[1] - mu) * rs * gm0.y + bt0.y, 0.f) + r0.y;
    y0.z = fmaxf((o[2] - mu) * rs * gm0.z + bt0.z, 0.f) + r0.z;
    y0.w = fmaxf((o[3] - mu) * rs * gm0.w + bt0.w, 0.f) + r0.w;
    y1.x = fmaxf((o[4] - mu) * rs * gm1.x + bt1.x, 0.f) + r1.x;
    y1.y = fmaxf((o[5] - mu) * rs * gm1.y + bt1.y, 0.f) + r1.y;
    y1.z = fmaxf((o[6] - mu) * rs * gm1.z + bt1.z, 0.f) + r1.z;
    y1.w = fmaxf((o[7] - mu) * rs * gm1.w + bt1.w, 0.f) + r1.w;
    *(float4*)(hrow)     = y0;
    *(float4*)(hrow + 4) = y1;
}

// ---------------------------------------------------------------------------
// Global mean pool. tcr -> pooled[b][0:128], cnt[b]; pep -> [128:256], cnt[B+b].
// ---------------------------------------------------------------------------
__global__ __launch_bounds__(256) void pool_kernel(const float* __restrict__ h,
                                                   const int* __restrict__ tb,
                                                   const int* __restrict__ pb,
                                                   float* __restrict__ pooled,
                                                   int* __restrict__ cnt,
                                                   int Nt, int N, int B) {
    int wave = threadIdx.x >> 6, lane = threadIdx.x & 63;
    int n = blockIdx.x * 4 + wave;
    if (n >= N) return;
    int b, off, ci;
    if (n < Nt) { b = tb[n];      off = 0;   ci = b; }
    else        { b = pb[n - Nt]; off = 128; ci = B + b; }
    float v0 = h[(size_t)n * 128 + lane];
    float v1 = h[(size_t)n * 128 + 64 + lane];
    atomicAdd(&pooled[(size_t)b * 256 + off + lane], v0);
    atomicAdd(&pooled[(size_t)b * 256 + off + 64 + lane], v1);
    if (lane == 0) atomicAdd(&cnt[ci], 1);
}

// ---------------------------------------------------------------------------
// Classifier MLP: [B,256] -> relu 128 -> relu 64 -> sigmoid 1. Block per row.
// ---------------------------------------------------------------------------
__global__ __launch_bounds__(128) void classifier_kernel(const float* __restrict__ pooled,
                                                         const int* __restrict__ cnt,
                                                         const float* __restrict__ Wc1,
                                                         const float* __restrict__ bc1,
                                                         const float* __restrict__ Wc2,
                                                         const float* __restrict__ bc2,
                                                         const float* __restrict__ Wc3,
                                                         const float* __restrict__ bc3,
                                                         float* __restrict__ outp, int B) {
    __shared__ float z[256];
    __shared__ float a1[128];
    __shared__ float a2[64];
    int r = blockIdx.x, t = threadIdx.x;
    float ct = (float)max(cnt[r], 1);
    float cp = (float)max(cnt[B + r], 1);
    z[t]       = pooled[(size_t)r * 256 + t] / ct;
    z[128 + t] = pooled[(size_t)r * 256 + 128 + t] / cp;
    __syncthreads();
    float acc = bc1[t];
    for (int k = 0; k < 256; ++k) acc = fmaf(z[k], Wc1[k * 128 + t], acc);
    a1[t] = fmaxf(acc, 0.f);
    __syncthreads();
    if (t < 64) {
        float a = bc2[t];
        for (int k = 0; k < 128; ++k) a = fmaf(a1[k], Wc2[k * 64 + t], a);
        a2[t] = fmaxf(a, 0.f);
    }
    __syncthreads();
    if (t < 64) {
        float p = a2[t] * Wc3[t];
#pragma unroll
        for (int k = 1; k < 64; k <<= 1) p += __shfl_xor(p, k);
        if (t == 0) outp[r] = 1.f / (1.f + __expf(-(p + bc3[0])));
    }
}

// ---------------------------------------------------------------------------
// Host orchestration — combined graph, fp16 MFMA GEMMs, fused softmax/gather.
// ---------------------------------------------------------------------------
extern "C" void kernel_launch(void* const* d_in, const int* in_sizes, int n_in,
                              void* d_out, int out_size, void* d_ws, size_t ws_size,
                              hipStream_t stream) {
    const float* tcr_x     = (const float*)d_in[0];
    const int*   tcr_ei    = (const int*)d_in[1];
    const int*   tcr_batch = (const int*)d_in[2];
    const float* pep_x     = (const float*)d_in[3];
    const int*   pep_ei    = (const int*)d_in[4];
    const int*   pep_batch = (const int*)d_in[5];
    const float* W_in      = (const float*)d_in[6];
    const float* b_in      = (const float*)d_in[7];
    const float* Wg        = (const float*)d_in[8];
    const float* bg        = (const float*)d_in[9];
    const float* att_src   = (const float*)d_in[10];
    const float* att_dst   = (const float*)d_in[11];
    const float* ln_gamma  = (const float*)d_in[12];
    const float* ln_beta   = (const float*)d_in[13];
    const float* Wc1       = (const float*)d_in[14];
    const float* bc1       = (const float*)d_in[15];
    const float* Wc2       = (const float*)d_in[16];
    const float* bc2       = (const float*)d_in[17];
    const float* Wc3       = (const float*)d_in[18];
    const float* bc3       = (const float*)d_in[19];

    const int Nt = in_sizes[0] / DIN;
    const int Et = in_sizes[1] / 2;
    const int Np = in_sizes[3] / DIN;
    const int Ep = in_sizes[4] / 2;
    const int B  = out_size;
    const int N  = Nt + Np;
    const int Etot = Et + Ep + N;

    char* w = (char*)d_ws;
    size_t o = 0;
    auto alloc = [&](size_t bytes) -> char* {
        size_t r = (o + 255) & ~(size_t)255;
        o = r + bytes;
        return w + r;
    };
    float*    pooled = (float*)alloc((size_t)B * 256 * 4);
    int*      cnt    = (int*)alloc((size_t)B * 2 * 4);
    float*    h_a    = (float*)alloc((size_t)N * 128 * 4);   // residual stream (f32)
    _Float16* h2h    = (_Float16*)alloc((size_t)N * 128 * 2); // projected feats (f16)
    _Float16* WtIn   = (_Float16*)alloc((size_t)128 * DIN * 2);
    _Float16* WtG    = (_Float16*)alloc((size_t)NLAYERS * 128 * 128 * 2);
    float*    ssrc   = (float*)alloc((size_t)N * 4 * 4);
    float*    sdst   = (float*)alloc((size_t)N * 4 * 4);
    int* rowptr      = (int*)alloc((size_t)(N + 1) * 4);
    int* cursor      = (int*)alloc((size_t)N * 4);
    int* deg         = (int*)alloc((size_t)N * 4);
    int* part        = (int*)alloc(256 * 4);
    int* col         = (int*)alloc((size_t)Etot * 4);
    (void)ws_size; (void)n_in;

    hipMemsetAsync(pooled, 0, (size_t)B * 256 * 4, stream);
    hipMemsetAsync(cnt, 0, (size_t)B * 2 * 4, stream);
    hipMemsetAsync(deg, 0, (size_t)N * 4, stream);

    // Weight prep (transpose + f16 cast)
    transpose_w<<<(128 * DIN + 255) / 256, 256, 0, stream>>>(W_in, WtIn, DIN);
    for (int i = 0; i < NLAYERS; ++i)
        transpose_w<<<(128 * 128 + 255) / 256, 256, 0, stream>>>(
            Wg + (size_t)i * HIDDIM * HIDDIM, WtG + (size_t)i * 128 * 128, 128);

    // CSR build (combined, built once, reused by all 3 layers)
    hist_kernel<<<(Etot + 255) / 256, 256, 0, stream>>>(tcr_ei, pep_ei, deg, Et, Ep, Nt, N);
    int nblk = (N + 1023) / 1024;
    scan_reduce<<<nblk, 256, 0, stream>>>(deg, part, N);
    scan_partials<<<1, 256, 0, stream>>>(part, rowptr, nblk, N);
    scan_final<<<nblk, 256, 0, stream>>>(deg, part, rowptr, cursor, N);
    // Owner-split fill: 4 owners x 512 chunks = 2048 blocks
    fill_kernel<<<NSPLIT * 512, 256, 0, stream>>>(tcr_ei, pep_ei, cursor, col,
                                                  Et, Ep, Nt, N, (float)NSPLIT / (float)N);

    // Input projection + relu -> combined residual stream (MFMA f16)
    mfma_gemm<0><<<Nt / 64, 256, 0, stream>>>(tcr_x, WtIn, b_in, h_a, DIN);
    mfma_gemm<0><<<Np / 64, 256, 0, stream>>>(pep_x, WtIn, b_in, h_a + (size_t)Nt * 128, DIN);

    for (int i = 0; i < NLAYERS; ++i) {
        mfma_gemm<1><<<N / 64, 256, 0, stream>>>(h_a, WtG + (size_t)i * 128 * 128,
                                                 nullptr, h2h, 128);
        scores_kernel<<<(N + 3) / 4, 256, 0, stream>>>((const __half2*)h2h,
                                                       att_src + i * NHEAD * CDIM,
                                                       att_dst + i * NHEAD * CDIM,
                                                       ssrc, sdst, N);
        gather_kernel<<<(N + 15) / 16, 256, 0, stream>>>((const f16x8*)h2h, ssrc, sdst,
                                                         rowptr, col, bg + i * HIDDIM,
                                                         ln_gamma + i * HIDDIM,
                                                         ln_beta + i * HIDDIM, h_a, N);
    }
    pool_kernel<<<(N + 3) / 4, 256, 0, stream>>>(h_a, tcr_batch, pep_batch, pooled, cnt, Nt, N, B);

    classifier_kernel<<<B, 128, 0, stream>>>(pooled, cnt, Wc1, bc1, Wc2, bc2,
                                             Wc3, bc3, (float*)d_out, B);
}

// Round 4
// 1148.071 us; speedup vs baseline: 1.2589x; 1.1259x over previous
//
#include <hip/hip_runtime.h>
#include <hip/hip_fp16.h>
#include <math.h>

// Problem constants: H=4 heads, C=32, HID=128, 3 layers, B=2048, D=480
#define NHEAD   4
#define CDIM    32
#define HIDDIM  128
#define NLAYERS 3
#define DIN     480
#define LN_EPS  1e-5f
#define NSPLIT  4    // dst-range owners for locality-split CSR fill

typedef _Float16 f16x8 __attribute__((ext_vector_type(8)));
typedef float    f32x4 __attribute__((ext_vector_type(4)));
typedef int      int4u __attribute__((ext_vector_type(4), aligned(4)));  // 4B-aligned int4 load

// ---------------------------------------------------------------------------
// Combined-graph CSR build. Node ids: tcr [0,Nt), pep [Nt,Nt+Np).
// ---------------------------------------------------------------------------
__global__ void hist_kernel(const int* __restrict__ tei, const int* __restrict__ pei,
                            int* __restrict__ deg, int Et, int Ep, int Nt, int N) {
    int i = blockIdx.x * 256 + threadIdx.x;
    int tot = Et + Ep + N;
    if (i >= tot) return;
    int d;
    if (i < Et)            d = tei[Et + i];
    else if (i < Et + Ep)  d = pei[Ep + (i - Et)] + Nt;
    else                   d = i - Et - Ep;
    atomicAdd(&deg[d], 1);
}

// Owner-split fill: blocks with blockIdx%NSPLIT==o only write edges whose dst
// falls in owner-range o (dst*NSPLIT/N). Confines each col region to ~2 XCDs'
// L2s over a short window so scattered 4B writes combine into full lines
// (WRITE_SIZE was 150MB for a 9.8MB payload before; ~6x less after).
__global__ __launch_bounds__(256) void fill_kernel(const int* __restrict__ tei,
                                                   const int* __restrict__ pei,
                                                   int* __restrict__ cursor,
                                                   int* __restrict__ col,
                                                   int Et, int Ep, int Nt, int N,
                                                   float oscale) {
    int oid    = blockIdx.x & (NSPLIT - 1);
    int chunk  = blockIdx.x / NSPLIT;
    int nchunk = gridDim.x / NSPLIT;
    int tot = Et + Ep + N;
    int per = (tot + nchunk - 1) / nchunk;
    int e0 = chunk * per;
    int e1 = min(e0 + per, tot);
    for (int i = e0 + (int)threadIdx.x; i < e1; i += 256) {
        int d;
        bool self = false;
        if (i < Et)           d = tei[Et + i];
        else if (i < Et + Ep) d = pei[Ep + (i - Et)] + Nt;
        else                { d = i - Et - Ep; self = true; }
        int owner = (int)((float)d * oscale);
        owner = owner > NSPLIT - 1 ? NSPLIT - 1 : owner;
        if (owner != oid) continue;
        int s;
        if (self)        s = d;
        else if (i < Et) s = tei[i];
        else             s = pei[i - Et] + Nt;
        int pos = atomicAdd(&cursor[d], 1);
        col[pos] = s;
    }
}

// ---------------------------------------------------------------------------
// Hierarchical exclusive scan: 1024 elems/block, int4 coalesced.
// ---------------------------------------------------------------------------
__global__ __launch_bounds__(256) void scan_reduce(const int* __restrict__ deg,
                                                   int* __restrict__ part, int N) {
    __shared__ int sm[256];
    int t = threadIdx.x;
    int base = blockIdx.x * 1024 + t * 4;
    int4 v = make_int4(0, 0, 0, 0);
    if (base + 3 < N) v = *(const int4*)(deg + base);
    else if (base < N) {
        v.x = deg[base];
        if (base + 1 < N) v.y = deg[base + 1];
        if (base + 2 < N) v.z = deg[base + 2];
    }
    sm[t] = v.x + v.y + v.z + v.w;
    __syncthreads();
    for (int off = 128; off >= 1; off >>= 1) {
        if (t < off) sm[t] += sm[t + off];
        __syncthreads();
    }
    if (t == 0) part[blockIdx.x] = sm[0];
}

__global__ __launch_bounds__(256) void scan_partials(int* __restrict__ part,
                                                     int* __restrict__ rowptr,
                                                     int npart, int N) {
    __shared__ int sm[256];
    int t = threadIdx.x;
    sm[t] = (t < npart) ? part[t] : 0;
    __syncthreads();
    for (int off = 1; off < 256; off <<= 1) {
        int u = (t >= off) ? sm[t - off] : 0;
        __syncthreads();
        sm[t] += u;
        __syncthreads();
    }
    if (t < npart) part[t] = (t == 0) ? 0 : sm[t - 1];
    if (t == 0) rowptr[N] = sm[255];
}

__global__ __launch_bounds__(256) void scan_final(const int* __restrict__ deg,
                                                  const int* __restrict__ part,
                                                  int* __restrict__ rowptr,
                                                  int* __restrict__ cursor, int N) {
    __shared__ int sm[256];
    int t = threadIdx.x;
    int base = blockIdx.x * 1024 + t * 4;
    int4 v = make_int4(0, 0, 0, 0);
    if (base + 3 < N) v = *(const int4*)(deg + base);
    else if (base < N) {
        v.x = deg[base];
        if (base + 1 < N) v.y = deg[base + 1];
        if (base + 2 < N) v.z = deg[base + 2];
    }
    sm[t] = v.x + v.y + v.z + v.w;
    __syncthreads();
    for (int off = 1; off < 256; off <<= 1) {
        int u = (t >= off) ? sm[t - off] : 0;
        __syncthreads();
        sm[t] += u;
        __syncthreads();
    }
    int run = ((t == 0) ? 0 : sm[t - 1]) + part[blockIdx.x];
    if (base < N)     { rowptr[base]     = run; cursor[base]     = run; run += v.x; }
    if (base + 1 < N) { rowptr[base + 1] = run; cursor[base + 1] = run; run += v.y; }
    if (base + 2 < N) { rowptr[base + 2] = run; cursor[base + 2] = run; run += v.z; }
    if (base + 3 < N) { rowptr[base + 3] = run; cursor[base + 3] = run; }
}

// ---------------------------------------------------------------------------
// Weight prep: W [K][128] f32 -> Wt [128][K] f16 (transposed, cast).
// ---------------------------------------------------------------------------
__global__ void transpose_w(const float* __restrict__ W, _Float16* __restrict__ Wt,
                            int K) {
    int idx = blockIdx.x * 256 + threadIdx.x;
    if (idx >= K * 128) return;
    int n = idx / K, k = idx - n * K;
    Wt[idx] = (_Float16)W[(size_t)k * 128 + n];
}

// ---------------------------------------------------------------------------
// MFMA fp16 GEMM: C[n,j] = act(A[n,:] @ W[:,j] (+bias)), 128 output cols.
// Block 256 (4 waves); tile 64 rows x 128 cols; K-step 32.
// Wt is pre-transposed [128][K] f16. A is f32, cast to f16 during staging.
// Fragment layouts (gfx950 16x16x32): A/B lane: [m|n=lane&15][k=quad*8+j];
// C/D lane: col=lane&15, row=quad*4+reg.
// OUT_F16=1: f16 out, no bias/act, PLUS fused attention scores: per-head dot
// of the f32 accumulator row with a_src/a_dst, 16-lane xor-reduce (head =
// nt>>1 since col = nt*16+lm, head = col>>5), one (row,head) write per lane.
// ---------------------------------------------------------------------------
#define ASTRIDE 40   // halves; 80 B row stride: 16B-aligned, 2-way banks (free)

template<int OUT_F16>
__global__ __launch_bounds__(256) void mfma_gemm(const float* __restrict__ A,
                                                 const _Float16* __restrict__ Wt,
                                                 const float* __restrict__ bias,
                                                 void* __restrict__ Cout,
                                                 const float* __restrict__ a_src,
                                                 const float* __restrict__ a_dst,
                                                 float* __restrict__ ssrc,
                                                 float* __restrict__ sdst,
                                                 int K) {
    __shared__ _Float16 As[64 * ASTRIDE];
    __shared__ _Float16 Ws[128 * ASTRIDE];
    const int tid  = threadIdx.x;
    const int bn   = blockIdx.x * 64;
    const int wave = tid >> 6, lane = tid & 63;
    const int lm   = lane & 15, q = lane >> 4;

    f32x4 acc[8];
#pragma unroll
    for (int i = 0; i < 8; ++i) acc[i] = (f32x4){0.f, 0.f, 0.f, 0.f};

    for (int kt = 0; kt < K; kt += 32) {
        // Stage A tile: 64 rows x 32 cols, f32 -> f16 (coalesced float4 loads)
#pragma unroll
        for (int p = 0; p < 2; ++p) {
            int f  = p * 256 + tid;          // float4 index in [0,512)
            int r  = f >> 3;
            int c4 = (f & 7) * 4;
            float4 v = *(const float4*)(A + (size_t)(bn + r) * K + kt + c4);
            _Float16* d = &As[r * ASTRIDE + c4];
            d[0] = (_Float16)v.x; d[1] = (_Float16)v.y;
            d[2] = (_Float16)v.z; d[3] = (_Float16)v.w;
        }
        // Stage Wt tile: 128 rows(n) x 32 k halves (straight copy, coalesced)
#pragma unroll
        for (int p = 0; p < 2; ++p) {
            int f   = p * 256 + tid;         // 8-half segment index in [0,512)
            int n   = f >> 2;
            int seg = (f & 3) * 8;
            *(float4*)(&Ws[n * ASTRIDE + seg]) =
                *(const float4*)(Wt + (size_t)n * K + kt + seg);
        }
        __syncthreads();
        f16x8 af = *(const f16x8*)(&As[(wave * 16 + lm) * ASTRIDE + q * 8]);
#pragma unroll
        for (int nt = 0; nt < 8; ++nt) {
            f16x8 bf = *(const f16x8*)(&Ws[(nt * 16 + lm) * ASTRIDE + q * 8]);
            acc[nt] = __builtin_amdgcn_mfma_f32_16x16x32_f16(af, bf, acc[nt], 0, 0, 0);
        }
        __syncthreads();
    }

    const int row0 = bn + wave * 16 + q * 4;
    if (OUT_F16) {
        _Float16* C = (_Float16*)Cout;
        float as[8], ad[8];
#pragma unroll
        for (int nt = 0; nt < 8; ++nt) {
            as[nt] = a_src[nt * 16 + lm];
            ad[nt] = a_dst[nt * 16 + lm];
        }
        float myS = 0.f, myD = 0.f;
#pragma unroll
        for (int i = 0; i < 4; ++i) {
            float ps[4], pd[4];
#pragma unroll
            for (int h = 0; h < 4; ++h) {
                ps[h] = as[2 * h] * acc[2 * h][i] + as[2 * h + 1] * acc[2 * h + 1][i];
                pd[h] = ad[2 * h] * acc[2 * h][i] + ad[2 * h + 1] * acc[2 * h + 1][i];
            }
#pragma unroll
            for (int k = 1; k < 16; k <<= 1) {
#pragma unroll
                for (int h = 0; h < 4; ++h) {
                    ps[h] += __shfl_xor(ps[h], k, 16);
                    pd[h] += __shfl_xor(pd[h], k, 16);
                }
            }
            if ((lm >> 2) == i) { myS = ps[lm & 3]; myD = pd[lm & 3]; }
#pragma unroll
            for (int nt = 0; nt < 8; ++nt)
                C[(size_t)(row0 + i) * 128 + nt * 16 + lm] = (_Float16)acc[nt][i];
        }
        int sr = (row0 + (lm >> 2)) * 4 + (lm & 3);
        ssrc[sr] = myS;
        sdst[sr] = myD;
    } else {
        float* C = (float*)Cout;
#pragma unroll
        for (int nt = 0; nt < 8; ++nt) {
            int c = nt * 16 + lm;
            float bv = bias[c];
#pragma unroll
            for (int i = 0; i < 4; ++i)
                C[(size_t)(row0 + i) * 128 + c] = fmaxf(acc[nt][i] + bv, 0.f);
        }
    }
}

// ---------------------------------------------------------------------------
// Fused gather with ONLINE softmax — 4 nodes per wave, 16 lanes per node,
// 8 channels per lane (one f16x8/dwordx4 value load per lane per edge).
// All scalar-ish per-edge work (col int4 load, ssrc load, leaky-relu, exp,
// online-max rescale) amortizes over 4 edges per wave-instruction.
// FMAs use (float)half * float + float so clang emits v_fma_mix_f32.
// Then /z + bias + LayerNorm (16-lane reduce) + ReLU + residual.
// ---------------------------------------------------------------------------
__global__ __launch_bounds__(256) void gather_kernel(const f16x8* __restrict__ h2v,
                                                     const float* __restrict__ ssrc,
                                                     const float* __restrict__ sdst,
                                                     const int* __restrict__ rowptr,
                                                     const int* __restrict__ col,
                                                     const float* __restrict__ bg,
                                                     const float* __restrict__ gamma,
                                                     const float* __restrict__ beta,
                                                     float* __restrict__ hio, int N) {
    int wave = threadIdx.x >> 6, lane = threadIdx.x & 63;
    int g = lane >> 4, t = lane & 15;       // group g handles node n; lane t -> ch [8t,8t+8)
    int n = blockIdx.x * 16 + wave * 4 + g;
    bool valid = n < N;
    int nn = valid ? n : 0;
    int head = t >> 2;
    int beg = rowptr[nn];
    int end = valid ? rowptr[nn + 1] : beg;
    float sd = sdst[nn * 4 + head];

    float m = -1e30f, z = 0.f;
    float a[8];
#pragma unroll
    for (int k = 0; k < 8; ++k) a[k] = 0.f;

    int j = beg;
    for (; j + 3 < end; j += 4) {
        int4u cv = *(const int4u*)(col + j);
        int s0 = cv.x, s1 = cv.y, s2 = cv.z, s3 = cv.w;
        float e0 = ssrc[s0 * 4 + head] + sd;
        float e1 = ssrc[s1 * 4 + head] + sd;
        float e2 = ssrc[s2 * 4 + head] + sd;
        float e3 = ssrc[s3 * 4 + head] + sd;
        f16x8 v0 = h2v[(size_t)s0 * 16 + t];
        f16x8 v1 = h2v[(size_t)s1 * 16 + t];
        f16x8 v2 = h2v[(size_t)s2 * 16 + t];
        f16x8 v3 = h2v[(size_t)s3 * 16 + t];
        e0 = fmaxf(e0, 0.2f * e0);          // leaky_relu(x) = max(x, 0.2x)
        e1 = fmaxf(e1, 0.2f * e1);
        e2 = fmaxf(e2, 0.2f * e2);
        e3 = fmaxf(e3, 0.2f * e3);
        float nm = fmaxf(fmaxf(fmaxf(e0, e1), fmaxf(e2, e3)), m);
        float r  = __expf(m - nm);          // 0 on first chunk, 1 if no new max
        m = nm;
        float p0 = __expf(e0 - nm);
        float p1 = __expf(e1 - nm);
        float p2 = __expf(e2 - nm);
        float p3 = __expf(e3 - nm);
        z = z * r + (p0 + p1 + p2 + p3);
#pragma unroll
        for (int k = 0; k < 8; ++k) a[k] *= r;
#pragma unroll
        for (int k = 0; k < 8; ++k) a[k] = fmaf((float)v0[k], p0, a[k]);
#pragma unroll
        for (int k = 0; k < 8; ++k) a[k] = fmaf((float)v1[k], p1, a[k]);
#pragma unroll
        for (int k = 0; k < 8; ++k) a[k] = fmaf((float)v2[k], p2, a[k]);
#pragma unroll
        for (int k = 0; k < 8; ++k) a[k] = fmaf((float)v3[k], p3, a[k]);
    }
    for (; j < end; ++j) {
        int s = col[j];
        float e = ssrc[s * 4 + head] + sd;
        e = fmaxf(e, 0.2f * e);
        f16x8 v = h2v[(size_t)s * 16 + t];
        float nm = fmaxf(m, e);
        float r  = __expf(m - nm);
        float p  = __expf(e - nm);
        m = nm;
        z = z * r + p;
#pragma unroll
        for (int k = 0; k < 8; ++k) a[k] = fmaf((float)v[k], p, a[k] * r);
    }

    if (!valid) return;
    float inv = 1.f / z;
    int c0 = t * 8;
    float4 bgv0 = *(const float4*)(bg + c0);
    float4 bgv1 = *(const float4*)(bg + c0 + 4);
    float o[8];
    o[0] = a[0] * inv + bgv0.x; o[1] = a[1] * inv + bgv0.y;
    o[2] = a[2] * inv + bgv0.z; o[3] = a[3] * inv + bgv0.w;
    o[4] = a[4] * inv + bgv1.x; o[5] = a[5] * inv + bgv1.y;
    o[6] = a[6] * inv + bgv1.z; o[7] = a[7] * inv + bgv1.w;
    float s = 0.f;
#pragma unroll
    for (int k = 0; k < 8; ++k) s += o[k];
#pragma unroll
    for (int k = 1; k < 16; k <<= 1) s += __shfl_xor(s, k, 16);
    float mu = s * (1.f / 128.f);
    float q = 0.f;
#pragma unroll
    for (int k = 0; k < 8; ++k) q += (o[k] - mu) * (o[k] - mu);
#pragma unroll
    for (int k = 1; k < 16; k <<= 1) q += __shfl_xor(q, k, 16);
    float rs = rsqrtf(q * (1.f / 128.f) + LN_EPS);
    float4 gm0 = *(const float4*)(gamma + c0);
    float4 gm1 = *(const float4*)(gamma + c0 + 4);
    float4 bt0 = *(const float4*)(beta + c0);
    float4 bt1 = *(const float4*)(beta + c0 + 4);
    float* hrow = hio + (size_t)n * 128 + c0;
    float4 r0 = *(const float4*)(hrow);
    float4 r1 = *(const float4*)(hrow + 4);
    float4 y0, y1;
    y0.x = fmaxf((o[0] - mu) * rs * gm0.x + bt0.x, 0.f) + r0.x;
    y0.y = fmaxf((o[1] - mu) * rs * gm0.y + bt0.y, 0.f) + r0.y;
    y0.z = fmaxf((o[2] - mu) * rs * gm0.z + bt0.z, 0.f) + r0.z;
    y0.w = fmaxf((o[3] - mu) * rs * gm0.w + bt0.w, 0.f) + r0.w;
    y1.x = fmaxf((o[4] - mu) * rs * gm1.x + bt1.x, 0.f) + r1.x;
    y1.y = fmaxf((o[5] - mu) * rs * gm1.y + bt1.y, 0.f) + r1.y;
    y1.z = fmaxf((o[6] - mu) * rs * gm1.z + bt1.z, 0.f) + r1.z;
    y1.w = fmaxf((o[7] - mu) * rs * gm1.w + bt1.w, 0.f) + r1.w;
    *(float4*)(hrow)     = y0;
    *(float4*)(hrow + 4) = y1;
}

// ---------------------------------------------------------------------------
// Atomic-free global mean pool. batch arrays are SORTED, so each batch
// element owns a contiguous node range: block = one (graph, side) pair,
// binary-search [beg,end), coalesced 512B row reads, one write per output.
// Divide by count here; classifier reads pooled directly (no cnt buffer).
// ---------------------------------------------------------------------------
__global__ __launch_bounds__(128) void pool_kernel(const float* __restrict__ h,
                                                   const int* __restrict__ tb,
                                                   const int* __restrict__ pb,
                                                   float* __restrict__ pooled,
                                                   int Nt, int Np, int B) {
    int blk = blockIdx.x;
    bool is_t = blk < B;
    int bb = is_t ? blk : blk - B;
    const int* __restrict__ arr = is_t ? tb : pb;
    int len  = is_t ? Nt : Np;
    int base = is_t ? 0 : Nt;
    int off  = is_t ? 0 : 128;
    // lower_bound(bb), lower_bound(bb+1) — all threads redundant (broadcast loads)
    int lo = 0, hi = len;
    while (lo < hi) { int mid = (lo + hi) >> 1; if (arr[mid] < bb) lo = mid + 1; else hi = mid; }
    int beg = lo;
    hi = len;
    while (lo < hi) { int mid = (lo + hi) >> 1; if (arr[mid] < bb + 1) lo = mid + 1; else hi = mid; }
    int end = lo;
    int t = threadIdx.x;
    float a0 = 0.f, a1 = 0.f, a2 = 0.f, a3 = 0.f;
    int n = beg;
    for (; n + 3 < end; n += 4) {
        a0 += h[(size_t)(base + n)     * 128 + t];
        a1 += h[(size_t)(base + n + 1) * 128 + t];
        a2 += h[(size_t)(base + n + 2) * 128 + t];
        a3 += h[(size_t)(base + n + 3) * 128 + t];
    }
    for (; n < end; ++n) a0 += h[(size_t)(base + n) * 128 + t];
    float s = (a0 + a1) + (a2 + a3);
    float invc = 1.f / (float)max(end - beg, 1);
    pooled[(size_t)bb * 256 + off + t] = s * invc;
}

// ---------------------------------------------------------------------------
// Classifier MLP: [B,256] -> relu 128 -> relu 64 -> sigmoid 1. Block per row.
// pooled is already count-normalized by pool_kernel.
// ---------------------------------------------------------------------------
__global__ __launch_bounds__(128) void classifier_kernel(const float* __restrict__ pooled,
                                                         const float* __restrict__ Wc1,
                                                         const float* __restrict__ bc1,
                                                         const float* __restrict__ Wc2,
                                                         const float* __restrict__ bc2,
                                                         const float* __restrict__ Wc3,
                                                         const float* __restrict__ bc3,
                                                         float* __restrict__ outp, int B) {
    __shared__ float z[256];
    __shared__ float a1[128];
    __shared__ float a2[64];
    int r = blockIdx.x, t = threadIdx.x;
    z[t]       = pooled[(size_t)r * 256 + t];
    z[128 + t] = pooled[(size_t)r * 256 + 128 + t];
    __syncthreads();
    float acc = bc1[t];
    for (int k = 0; k < 256; ++k) acc = fmaf(z[k], Wc1[k * 128 + t], acc);
    a1[t] = fmaxf(acc, 0.f);
    __syncthreads();
    if (t < 64) {
        float a = bc2[t];
        for (int k = 0; k < 128; ++k) a = fmaf(a1[k], Wc2[k * 64 + t], a);
        a2[t] = fmaxf(a, 0.f);
    }
    __syncthreads();
    if (t < 64) {
        float p = a2[t] * Wc3[t];
#pragma unroll
        for (int k = 1; k < 64; k <<= 1) p += __shfl_xor(p, k);
        if (t == 0) outp[r] = 1.f / (1.f + __expf(-(p + bc3[0])));
    }
}

// ---------------------------------------------------------------------------
// Host orchestration — combined graph, fp16 MFMA GEMMs with fused scores,
// fused online-softmax gather, atomic-free pool.
// ---------------------------------------------------------------------------
extern "C" void kernel_launch(void* const* d_in, const int* in_sizes, int n_in,
                              void* d_out, int out_size, void* d_ws, size_t ws_size,
                              hipStream_t stream) {
    const float* tcr_x     = (const float*)d_in[0];
    const int*   tcr_ei    = (const int*)d_in[1];
    const int*   tcr_batch = (const int*)d_in[2];
    const float* pep_x     = (const float*)d_in[3];
    const int*   pep_ei    = (const int*)d_in[4];
    const int*   pep_batch = (const int*)d_in[5];
    const float* W_in      = (const float*)d_in[6];
    const float* b_in      = (const float*)d_in[7];
    const float* Wg        = (const float*)d_in[8];
    const float* bg        = (const float*)d_in[9];
    const float* att_src   = (const float*)d_in[10];
    const float* att_dst   = (const float*)d_in[11];
    const float* ln_gamma  = (const float*)d_in[12];
    const float* ln_beta   = (const float*)d_in[13];
    const float* Wc1       = (const float*)d_in[14];
    const float* bc1       = (const float*)d_in[15];
    const float* Wc2       = (const float*)d_in[16];
    const float* bc2       = (const float*)d_in[17];
    const float* Wc3       = (const float*)d_in[18];
    const float* bc3       = (const float*)d_in[19];

    const int Nt = in_sizes[0] / DIN;
    const int Et = in_sizes[1] / 2;
    const int Np = in_sizes[3] / DIN;
    const int Ep = in_sizes[4] / 2;
    const int B  = out_size;
    const int N  = Nt + Np;
    const int Etot = Et + Ep + N;

    char* w = (char*)d_ws;
    size_t o = 0;
    auto alloc = [&](size_t bytes) -> char* {
        size_t r = (o + 255) & ~(size_t)255;
        o = r + bytes;
        return w + r;
    };
    float*    pooled = (float*)alloc((size_t)B * 256 * 4);
    float*    h_a    = (float*)alloc((size_t)N * 128 * 4);   // residual stream (f32)
    _Float16* h2h    = (_Float16*)alloc((size_t)N * 128 * 2); // projected feats (f16)
    _Float16* WtIn   = (_Float16*)alloc((size_t)128 * DIN * 2);
    _Float16* WtG    = (_Float16*)alloc((size_t)NLAYERS * 128 * 128 * 2);
    float*    ssrc   = (float*)alloc((size_t)N * 4 * 4);
    float*    sdst   = (float*)alloc((size_t)N * 4 * 4);
    int* rowptr      = (int*)alloc((size_t)(N + 1) * 4);
    int* cursor      = (int*)alloc((size_t)N * 4);
    int* deg         = (int*)alloc((size_t)N * 4);
    int* part        = (int*)alloc(256 * 4);
    int* col         = (int*)alloc((size_t)Etot * 4);
    (void)ws_size; (void)n_in;

    hipMemsetAsync(deg, 0, (size_t)N * 4, stream);

    // Weight prep (transpose + f16 cast)
    transpose_w<<<(128 * DIN + 255) / 256, 256, 0, stream>>>(W_in, WtIn, DIN);
    for (int i = 0; i < NLAYERS; ++i)
        transpose_w<<<(128 * 128 + 255) / 256, 256, 0, stream>>>(
            Wg + (size_t)i * HIDDIM * HIDDIM, WtG + (size_t)i * 128 * 128, 128);

    // CSR build (combined, built once, reused by all 3 layers)
    hist_kernel<<<(Etot + 255) / 256, 256, 0, stream>>>(tcr_ei, pep_ei, deg, Et, Ep, Nt, N);
    int nblk = (N + 1023) / 1024;
    scan_reduce<<<nblk, 256, 0, stream>>>(deg, part, N);
    scan_partials<<<1, 256, 0, stream>>>(part, rowptr, nblk, N);
    scan_final<<<nblk, 256, 0, stream>>>(deg, part, rowptr, cursor, N);
    // Owner-split fill: 4 owners x 512 chunks = 2048 blocks
    fill_kernel<<<NSPLIT * 512, 256, 0, stream>>>(tcr_ei, pep_ei, cursor, col,
                                                  Et, Ep, Nt, N, (float)NSPLIT / (float)N);

    // Input projection + relu -> combined residual stream (MFMA f16)
    mfma_gemm<0><<<Nt / 64, 256, 0, stream>>>(tcr_x, WtIn, b_in, h_a,
                                              nullptr, nullptr, nullptr, nullptr, DIN);
    mfma_gemm<0><<<Np / 64, 256, 0, stream>>>(pep_x, WtIn, b_in, h_a + (size_t)Nt * 128,
                                              nullptr, nullptr, nullptr, nullptr, DIN);

    for (int i = 0; i < NLAYERS; ++i) {
        mfma_gemm<1><<<N / 64, 256, 0, stream>>>(h_a, WtG + (size_t)i * 128 * 128,
                                                 nullptr, h2h,
                                                 att_src + i * NHEAD * CDIM,
                                                 att_dst + i * NHEAD * CDIM,
                                                 ssrc, sdst, 128);
        gather_kernel<<<(N + 15) / 16, 256, 0, stream>>>((const f16x8*)h2h, ssrc, sdst,
                                                         rowptr, col, bg + i * HIDDIM,
                                                         ln_gamma + i * HIDDIM,
                                                         ln_beta + i * HIDDIM, h_a, N);
    }
    pool_kernel<<<2 * B, 128, 0, stream>>>(h_a, tcr_batch, pep_batch, pooled, Nt, Np, B);

    classifier_kernel<<<B, 128, 0, stream>>>(pooled, Wc1, bc1, Wc2, bc2,
                                             Wc3, bc3, (float*)d_out, B);
}